// Round 2
// baseline (2293.366 us; speedup 1.0000x reference)
//
#include <hip/hip_runtime.h>
#include <hip/hip_fp16.h>

#define NDIM  4096
#define LSTEPS 50
#define ANUM   4
#define NMATS  5   // T_base + 4 A_mats

// ---------------------------------------------------------------------------
// init: out[] = 0; x1 = b; out[0] = r . b   (step 0 of the scan: x0 == 0)
// ---------------------------------------------------------------------------
__global__ void init_kernel(const float* __restrict__ b, const float* __restrict__ r,
                            float* __restrict__ x1, float* __restrict__ out) {
    const int tid = threadIdx.x;
    if (tid < LSTEPS) out[tid] = 0.0f;   // out[0] overwritten below (thread 0 only)
    float part = 0.0f;
    for (int i = tid; i < NDIM; i += 256) {
        float bi = b[i];
        x1[i] = bi;
        part += r[i] * bi;
    }
#pragma unroll
    for (int off = 32; off > 0; off >>= 1) part += __shfl_xor(part, off, 64);
    __shared__ float sm[4];
    const int wave = tid >> 6, lane = tid & 63;
    if (lane == 0) sm[wave] = part;
    __syncthreads();
    if (tid == 0) out[0] = sm[0] + sm[1] + sm[2] + sm[3];
}

// ---------------------------------------------------------------------------
// fp32 -> fp16 conversion of [T_base | A_mats] into workspace.
// ---------------------------------------------------------------------------
__global__ void conv_kernel(const float* __restrict__ Tb, const float* __restrict__ Am,
                            uint4* __restrict__ dst) {
    const size_t idx  = (size_t)blockIdx.x * 256 + threadIdx.x;
    const size_t base = idx * 8;
    const size_t nn   = (size_t)NDIM * NDIM;
    const float4* src;
    size_t off4;
    if (base < nn) { src = (const float4*)Tb; off4 = base >> 2; }
    else           { src = (const float4*)Am; off4 = (base - nn) >> 2; }
    const float4 f0 = src[off4];
    const float4 f1 = src[off4 + 1];
    union { uint4 v; __half h[8]; } pk;
    pk.h[0] = __float2half(f0.x); pk.h[1] = __float2half(f0.y);
    pk.h[2] = __float2half(f0.z); pk.h[3] = __float2half(f0.w);
    pk.h[4] = __float2half(f1.x); pk.h[5] = __float2half(f1.y);
    pk.h[6] = __float2half(f1.z); pk.h[7] = __float2half(f1.w);
    dst[idx] = pk.v;
}

// ---------------------------------------------------------------------------
// One recurrence step, fp16 matrices, split-K x2 for full occupancy:
//   y = T_base@x + sum_a act[a]*(A_a@x) + b ;  x_out = y ;  out[t] += r.y
// 2048 blocks x 256 threads; block handles 2 rows; each wave handles half the
// columns of one row (waves 0,1 -> row0; 2,3 -> row1). 8 blocks/CU resident
// (LDS 16KB, 32 waves/CU) -> 2x the in-flight loads vs 1-wave-per-row.
// ---------------------------------------------------------------------------
__global__ __launch_bounds__(256) void step_half(
        const uint4* __restrict__ mats,   // [NMATS][N][N] halves, 8/uint4
        const float* __restrict__ x_in,
        float*       __restrict__ x_out,
        const float* __restrict__ b,
        const float* __restrict__ r,
        const float* __restrict__ traj,
        float*       __restrict__ out, int t) {
    __shared__ float xs[NDIM];
    __shared__ float parts[4];
    const int tid = threadIdx.x;
    {
        const float4* xv  = (const float4*)x_in;
        float4*       xsv = (float4*)xs;
#pragma unroll
        for (int i = 0; i < 4; i++) xsv[tid + 256 * i] = xv[tid + 256 * i];
    }
    __syncthreads();

    const float a0 = traj[t * ANUM + 0], a1 = traj[t * ANUM + 1],
                a2 = traj[t * ANUM + 2], a3 = traj[t * ANUM + 3];

    const int wave  = tid >> 6, lane = tid & 63;
    const int row   = blockIdx.x * 2 + (wave >> 1);
    const int kHalf = wave & 1;
    const size_t matq = (size_t)NDIM * NDIM / 8;          // uint4 per matrix
    const size_t base = (size_t)row * (NDIM / 8) + (size_t)kHalf * 256;

    float acc[NMATS] = {0.f, 0.f, 0.f, 0.f, 0.f};
#pragma unroll
    for (int c = 0; c < 4; c++) {
        const float4* xp = (const float4*)(&xs[kHalf * 2048 + c * 512 + lane * 8]);
        const float4 xa = xp[0], xb = xp[1];
        const size_t qi = base + (size_t)c * 64 + lane;
#pragma unroll
        for (int m = 0; m < NMATS; m++) {
            union { uint4 v; __half2 h2[4]; } u;
            u.v = mats[(size_t)m * matq + qi];
            const float2 p0 = __half22float2(u.h2[0]);
            const float2 p1 = __half22float2(u.h2[1]);
            const float2 p2 = __half22float2(u.h2[2]);
            const float2 p3 = __half22float2(u.h2[3]);
            float a = acc[m];
            a = fmaf(p0.x, xa.x, a); a = fmaf(p0.y, xa.y, a);
            a = fmaf(p1.x, xa.z, a); a = fmaf(p1.y, xa.w, a);
            a = fmaf(p2.x, xb.x, a); a = fmaf(p2.y, xb.y, a);
            a = fmaf(p3.x, xb.z, a); a = fmaf(p3.y, xb.w, a);
            acc[m] = a;
        }
    }
    float s = acc[0] + a0 * acc[1] + a1 * acc[2] + a2 * acc[3] + a3 * acc[4];
#pragma unroll
    for (int off = 32; off > 0; off >>= 1) s += __shfl_xor(s, off, 64);
    if (lane == 0) parts[wave] = s;
    __syncthreads();
    if (tid == 0) {
        const int row0 = blockIdx.x * 2;
        const float y0 = parts[0] + parts[1] + b[row0];
        const float y1 = parts[2] + parts[3] + b[row0 + 1];
        x_out[row0]     = y0;
        x_out[row0 + 1] = y1;
        atomicAdd(out + t, r[row0] * y0 + r[row0 + 1] * y1);
    }
}

// ---------------------------------------------------------------------------
// Fallback: fp32 matrices straight from inputs (only if ws too small).
// ---------------------------------------------------------------------------
__global__ __launch_bounds__(256) void step_f32(
        const float* __restrict__ Tb, const float* __restrict__ Am,
        const float* __restrict__ x_in, float* __restrict__ x_out,
        const float* __restrict__ b, const float* __restrict__ r,
        const float* __restrict__ traj, float* __restrict__ out, int t) {
    __shared__ float xs[NDIM];
    __shared__ float parts[4];
    const int tid = threadIdx.x;
    {
        const float4* xv  = (const float4*)x_in;
        float4*       xsv = (float4*)xs;
#pragma unroll
        for (int i = 0; i < 4; i++) xsv[tid + 256 * i] = xv[tid + 256 * i];
    }
    __syncthreads();

    const float a0 = traj[t * ANUM + 0], a1 = traj[t * ANUM + 1],
                a2 = traj[t * ANUM + 2], a3 = traj[t * ANUM + 3];

    const int wave = tid >> 6, lane = tid & 63;
    const int row  = blockIdx.x * 4 + wave;
    const size_t nn = (size_t)NDIM * NDIM;
    const float4* mat[NMATS] = {
        (const float4*)Tb, (const float4*)Am, (const float4*)(Am + nn),
        (const float4*)(Am + 2 * nn), (const float4*)(Am + 3 * nn)};
    const size_t rowq = (size_t)row * (NDIM / 4);

    float acc[NMATS] = {0.f, 0.f, 0.f, 0.f, 0.f};
#pragma unroll
    for (int c = 0; c < 16; c++) {
        const float4 xa = *(const float4*)(&xs[c * 256 + lane * 4]);
        const size_t qi = rowq + (size_t)c * 64 + lane;
#pragma unroll
        for (int m = 0; m < NMATS; m++) {
            const float4 v = mat[m][qi];
            float a = acc[m];
            a = fmaf(v.x, xa.x, a); a = fmaf(v.y, xa.y, a);
            a = fmaf(v.z, xa.z, a); a = fmaf(v.w, xa.w, a);
            acc[m] = a;
        }
    }
    float s = acc[0] + a0 * acc[1] + a1 * acc[2] + a2 * acc[3] + a3 * acc[4];
#pragma unroll
    for (int off = 32; off > 0; off >>= 1) s += __shfl_xor(s, off, 64);
    if (lane == 0) {
        const float y = s + b[row];
        x_out[row] = y;
        parts[wave] = r[row] * y;
    }
    __syncthreads();
    if (tid == 0) atomicAdd(out + t, parts[0] + parts[1] + parts[2] + parts[3]);
}

// ---------------------------------------------------------------------------
extern "C" void kernel_launch(void* const* d_in, const int* in_sizes, int n_in,
                              void* d_out, int out_size, void* d_ws, size_t ws_size,
                              hipStream_t stream) {
    // inputs per setup_inputs(): init_states(N) [unused], trajectories(L*ANUM),
    // T_base(N*N), A_mats(ANUM*N*N), b(N), r(N)
    const float* traj = (const float*)d_in[1];
    const float* Tb   = (const float*)d_in[2];
    const float* Am   = (const float*)d_in[3];
    const float* b    = (const float*)d_in[4];
    const float* r    = (const float*)d_in[5];
    float* out = (float*)d_out;

    const size_t matBytes = (size_t)NMATS * NDIM * NDIM * sizeof(__half); // 160 MiB
    const size_t xBytes   = 2 * (size_t)NDIM * sizeof(float);
    const bool useHalf = ws_size >= matBytes + xBytes;

    if (useHalf) {
        uint4* mats = (uint4*)d_ws;
        float* x0 = (float*)((char*)d_ws + matBytes);
        float* x1 = x0 + NDIM;
        init_kernel<<<1, 256, 0, stream>>>(b, r, x0, out);
        const int convBlocks = (int)(((size_t)NMATS * NDIM * NDIM / 8) / 256); // 40960
        conv_kernel<<<convBlocks, 256, 0, stream>>>(Tb, Am, mats);
        for (int t = 1; t < LSTEPS; t++) {
            float* xi = (t & 1) ? x0 : x1;
            float* xo = (t & 1) ? x1 : x0;
            step_half<<<NDIM / 2, 256, 0, stream>>>(mats, xi, xo, b, r, traj, out, t);
        }
    } else {
        float* x0 = (float*)d_ws;
        float* x1 = x0 + NDIM;
        init_kernel<<<1, 256, 0, stream>>>(b, r, x0, out);
        for (int t = 1; t < LSTEPS; t++) {
            float* xi = (t & 1) ? x0 : x1;
            float* xo = (t & 1) ? x1 : x0;
            step_f32<<<NDIM / 4, 256, 0, stream>>>(Tb, Am, xi, xo, b, r, traj, out, t);
        }
    }
}

// Round 4
// 1709.461 us; speedup vs baseline: 1.3416x; 1.3416x over previous
//
#include <hip/hip_runtime.h>
#include <hip/hip_fp16.h>

#define NDIM   4096
#define LSTEPS 50
#define ANUM   4
#define NN     ((size_t)NDIM * (size_t)NDIM)
#define CHUNK1 25   // T_1 .. T_25
#define CHUNK2 24   // T_26 .. T_49

// native vector types for nontemporal builtins (HIP_vector_type is a class
// and __builtin_nontemporal_load rejects it)
typedef unsigned int nuint4 __attribute__((ext_vector_type(4)));
typedef float        nfloat4 __attribute__((ext_vector_type(4)));

// ---------------------------------------------------------------------------
// init: x1 = b   (x0 == 0 so step 0 of the scan is just x1 = b)
// ---------------------------------------------------------------------------
__global__ void init_kernel(const float* __restrict__ b, float* __restrict__ x1) {
    const int tid = threadIdx.x;
    const float4* bv = (const float4*)b;
    float4* xv = (float4*)x1;
#pragma unroll
    for (int i = 0; i < 4; i++) xv[tid + 256 * i] = bv[tid + 256 * i];
}

// ---------------------------------------------------------------------------
// combine: for t in [t0, t0+C): T_t = T_base + sum_a act[t,a]*A_a  -> fp16.
// Each thread owns 8 consecutive elements; reads 5x32B fp32, writes C x 16B.
// 8192 blocks x 256 threads. Memory-bound: (320 MB read + C*33.5 MB write).
// ---------------------------------------------------------------------------
__global__ __launch_bounds__(256) void combine_kernel(
        const float* __restrict__ Tb, const float* __restrict__ Am,
        const float* __restrict__ traj, uint4* __restrict__ outbuf,
        int t0, int C) {
    __shared__ float sact[CHUNK1 * ANUM];
    const int tid = threadIdx.x;
    if (tid < C * ANUM)
        sact[tid] = traj[(size_t)(t0 + tid / ANUM) * ANUM + (tid % ANUM)];
    __syncthreads();

    const size_t gtid = (size_t)blockIdx.x * 256 + tid;  // uint4-out index (8 elems)
    const size_t e4   = gtid * 2;                        // float4 index
    const float4* tb4 = (const float4*)Tb;
    const float4* am4 = (const float4*)Am;
    const size_t m4 = NN / 4;

    union F8 { float4 f4[2]; float f[8]; };
    F8 tb, am[4];
    tb.f4[0] = tb4[e4]; tb.f4[1] = tb4[e4 + 1];
#pragma unroll
    for (int m = 0; m < 4; m++) {
        am[m].f4[0] = am4[(size_t)m * m4 + e4];
        am[m].f4[1] = am4[(size_t)m * m4 + e4 + 1];
    }

    const size_t matq = NN / 8;
    for (int t = 0; t < C; t++) {
        const float w0 = sact[t * 4 + 0], w1 = sact[t * 4 + 1],
                    w2 = sact[t * 4 + 2], w3 = sact[t * 4 + 3];
        union { uint4 v; __half h[8]; } pk;
#pragma unroll
        for (int j = 0; j < 8; j++) {
            float v = tb.f[j];
            v = fmaf(w0, am[0].f[j], v);
            v = fmaf(w1, am[1].f[j], v);
            v = fmaf(w2, am[2].f[j], v);
            v = fmaf(w3, am[3].f[j], v);
            pk.h[j] = __float2half(v);
        }
        outbuf[(size_t)t * matq + gtid] = pk.v;
    }
}

// ---------------------------------------------------------------------------
// One recurrence step with a pre-combined fp16 matrix:
//   y = T_t @ x + b ; x_out = y
// 1025 blocks x 256 threads. Blocks 0..1023: one wave per row, matrix loads
// nontemporal (streaming, zero reuse), x read straight from global (16 KB,
// L1/L2-resident) -- no LDS staging, no __syncthreads, no atomics.
// Block 1024: computes out[t-1] = r . x_in (the PREVIOUS step's reward) so
// each out element is written exactly once, atomic-free.
// ---------------------------------------------------------------------------
__global__ __launch_bounds__(256) void step_kernel(
        const uint4* __restrict__ Tt,    // [N][N/8] (8 halves per uint4)
        const float* __restrict__ x_in,
        float*       __restrict__ x_out,
        const float* __restrict__ b,
        const float* __restrict__ r,
        float*       __restrict__ out, int t) {
    const int tid  = threadIdx.x;
    const int wave = tid >> 6, lane = tid & 63;

    if (blockIdx.x == gridDim.x - 1) {
        __shared__ float parts[4];
        float s = 0.f;
#pragma unroll
        for (int i = 0; i < 16; i++) {
            const int idx = tid + 256 * i;
            s = fmaf(r[idx], x_in[idx], s);
        }
#pragma unroll
        for (int off = 32; off > 0; off >>= 1) s += __shfl_xor(s, off, 64);
        if (lane == 0) parts[wave] = s;
        __syncthreads();
        if (tid == 0) out[t - 1] = parts[0] + parts[1] + parts[2] + parts[3];
        return;
    }

    const int row = blockIdx.x * 4 + wave;
    const size_t rowq = (size_t)row * (NDIM / 8);
    const nuint4* Tn = (const nuint4*)Tt;
    const float4* xv = (const float4*)x_in;

    float acc = 0.f;
#pragma unroll
    for (int c = 0; c < 8; c++) {
        const int ci = c * 64 + lane;
        const nuint4 tv = __builtin_nontemporal_load(&Tn[rowq + ci]);
        const float4 xa = xv[ci * 2];
        const float4 xb = xv[ci * 2 + 1];
        union { nuint4 v; __half2 h2[4]; } u; u.v = tv;
        const float2 p0 = __half22float2(u.h2[0]);
        const float2 p1 = __half22float2(u.h2[1]);
        const float2 p2 = __half22float2(u.h2[2]);
        const float2 p3 = __half22float2(u.h2[3]);
        acc = fmaf(p0.x, xa.x, acc); acc = fmaf(p0.y, xa.y, acc);
        acc = fmaf(p1.x, xa.z, acc); acc = fmaf(p1.y, xa.w, acc);
        acc = fmaf(p2.x, xb.x, acc); acc = fmaf(p2.y, xb.y, acc);
        acc = fmaf(p3.x, xb.z, acc); acc = fmaf(p3.y, xb.w, acc);
    }
#pragma unroll
    for (int off = 32; off > 0; off >>= 1) acc += __shfl_xor(acc, off, 64);
    if (lane == 0) x_out[row] = acc + b[row];
}

// ---------------------------------------------------------------------------
// final: out[L-1] = r . x_final   (one block)
// ---------------------------------------------------------------------------
__global__ void dot_kernel(const float* __restrict__ x, const float* __restrict__ r,
                           float* __restrict__ out_elem) {
    const int tid = threadIdx.x;
    const int wave = tid >> 6, lane = tid & 63;
    __shared__ float parts[4];
    float s = 0.f;
#pragma unroll
    for (int i = 0; i < 16; i++) {
        const int idx = tid + 256 * i;
        s = fmaf(r[idx], x[idx], s);
    }
#pragma unroll
    for (int off = 32; off > 0; off >>= 1) s += __shfl_xor(s, off, 64);
    if (lane == 0) parts[wave] = s;
    __syncthreads();
    if (tid == 0) *out_elem = parts[0] + parts[1] + parts[2] + parts[3];
}

// ---------------------------------------------------------------------------
// Fallback step (only if ws can't hold a chunk): fp32 sources, 5 streams,
// same atomic-free fold structure. 1025 blocks x 256 threads.
// ---------------------------------------------------------------------------
__global__ __launch_bounds__(256) void step_f32_kernel(
        const float* __restrict__ Tb, const float* __restrict__ Am,
        const float* __restrict__ x_in, float* __restrict__ x_out,
        const float* __restrict__ b, const float* __restrict__ r,
        const float* __restrict__ traj, float* __restrict__ out, int t) {
    const int tid  = threadIdx.x;
    const int wave = tid >> 6, lane = tid & 63;

    if (blockIdx.x == gridDim.x - 1) {
        __shared__ float parts[4];
        float s = 0.f;
#pragma unroll
        for (int i = 0; i < 16; i++) {
            const int idx = tid + 256 * i;
            s = fmaf(r[idx], x_in[idx], s);
        }
#pragma unroll
        for (int off = 32; off > 0; off >>= 1) s += __shfl_xor(s, off, 64);
        if (lane == 0) parts[wave] = s;
        __syncthreads();
        if (tid == 0) out[t - 1] = parts[0] + parts[1] + parts[2] + parts[3];
        return;
    }

    const float a0 = traj[t * ANUM + 0], a1 = traj[t * ANUM + 1],
                a2 = traj[t * ANUM + 2], a3 = traj[t * ANUM + 3];
    const int row = blockIdx.x * 4 + wave;
    const nfloat4* mat[5] = {
        (const nfloat4*)Tb, (const nfloat4*)Am, (const nfloat4*)(Am + NN),
        (const nfloat4*)(Am + 2 * NN), (const nfloat4*)(Am + 3 * NN)};
    const size_t rowq = (size_t)row * (NDIM / 4);
    const float4* xv = (const float4*)x_in;

    float acc[5] = {0.f, 0.f, 0.f, 0.f, 0.f};
#pragma unroll
    for (int c = 0; c < 16; c++) {
        const int ci = c * 64 + lane;
        const float4 xa = xv[ci];
        const size_t qi = rowq + ci;
#pragma unroll
        for (int m = 0; m < 5; m++) {
            const nfloat4 v = __builtin_nontemporal_load(&mat[m][qi]);
            float a = acc[m];
            a = fmaf(v.x, xa.x, a); a = fmaf(v.y, xa.y, a);
            a = fmaf(v.z, xa.z, a); a = fmaf(v.w, xa.w, a);
            acc[m] = a;
        }
    }
    float s = acc[0] + a0 * acc[1] + a1 * acc[2] + a2 * acc[3] + a3 * acc[4];
#pragma unroll
    for (int off = 32; off > 0; off >>= 1) s += __shfl_xor(s, off, 64);
    if (lane == 0) x_out[row] = s + b[row];
}

// ---------------------------------------------------------------------------
extern "C" void kernel_launch(void* const* d_in, const int* in_sizes, int n_in,
                              void* d_out, int out_size, void* d_ws, size_t ws_size,
                              hipStream_t stream) {
    // inputs: init_states(N) [unused], trajectories(L*ANUM), T_base(N*N),
    //         A_mats(ANUM*N*N), b(N), r(N)
    const float* traj = (const float*)d_in[1];
    const float* Tb   = (const float*)d_in[2];
    const float* Am   = (const float*)d_in[3];
    const float* b    = (const float*)d_in[4];
    const float* r    = (const float*)d_in[5];
    float* out = (float*)d_out;

    const size_t chunkBytes = (size_t)CHUNK1 * NN * sizeof(__half);  // 838.9 MB
    const size_t xBytes     = 2 * (size_t)NDIM * sizeof(float);
    const bool useChunks = ws_size >= chunkBytes + xBytes;

    if (useChunks) {
        uint4* chunk = (uint4*)d_ws;
        float* x0 = (float*)((char*)d_ws + chunkBytes);
        float* x1 = x0 + NDIM;
        const size_t matq = NN / 8;
        const int combBlocks = (int)(matq / 256);  // 8192

        init_kernel<<<1, 256, 0, stream>>>(b, x0);  // x0 = x_1 = b

        // chunk 1: T_1..T_25, then steps 1..25
        combine_kernel<<<combBlocks, 256, 0, stream>>>(Tb, Am, traj, chunk, 1, CHUNK1);
        for (int t = 1; t <= CHUNK1; t++) {
            float* xi = (t & 1) ? x0 : x1;
            float* xo = (t & 1) ? x1 : x0;
            step_kernel<<<NDIM / 4 + 1, 256, 0, stream>>>(
                chunk + (size_t)(t - 1) * matq, xi, xo, b, r, out, t);
        }
        // chunk 2: T_26..T_49, then steps 26..49
        combine_kernel<<<combBlocks, 256, 0, stream>>>(Tb, Am, traj, chunk,
                                                       CHUNK1 + 1, CHUNK2);
        for (int t = CHUNK1 + 1; t < LSTEPS; t++) {
            float* xi = (t & 1) ? x0 : x1;
            float* xo = (t & 1) ? x1 : x0;
            step_kernel<<<NDIM / 4 + 1, 256, 0, stream>>>(
                chunk + (size_t)(t - CHUNK1 - 1) * matq, xi, xo, b, r, out, t);
        }
        // x_50 lives in the buffer written by step t=49 (odd -> x1)
        dot_kernel<<<1, 256, 0, stream>>>(x1, r, out + (LSTEPS - 1));
    } else {
        float* x0 = (float*)d_ws;
        float* x1 = x0 + NDIM;
        init_kernel<<<1, 256, 0, stream>>>(b, x0);
        for (int t = 1; t < LSTEPS; t++) {
            float* xi = (t & 1) ? x0 : x1;
            float* xo = (t & 1) ? x1 : x0;
            step_f32_kernel<<<NDIM / 4 + 1, 256, 0, stream>>>(Tb, Am, xi, xo, b, r,
                                                              traj, out, t);
        }
        dot_kernel<<<1, 256, 0, stream>>>(x1, r, out + (LSTEPS - 1));
    }
}

// Round 5
// 1602.622 us; speedup vs baseline: 1.4310x; 1.0667x over previous
//
#include <hip/hip_runtime.h>
#include <hip/hip_fp16.h>

#define NDIM   4096
#define LSTEPS 50
#define ANUM   4
#define NN     ((size_t)NDIM * (size_t)NDIM)
#define ROWQ   512            // uint4 per matrix row (4096 halves / 8)
#define RSTRIDE (5 * ROWQ)    // uint4 per row-group in interleaved [row][mat][col] layout

// native vector type for reinterpret tricks
typedef unsigned int nuint4 __attribute__((ext_vector_type(4)));

// ---------------------------------------------------------------------------
// init: x1 = b   (x0 == 0 so step 0 of the scan is just x1 = b)
// ---------------------------------------------------------------------------
__global__ void init_kernel(const float* __restrict__ b, float* __restrict__ x1) {
    const int tid = threadIdx.x;
    const float4* bv = (const float4*)b;
    float4* xv = (float4*)x1;
#pragma unroll
    for (int i = 0; i < 4; i++) xv[tid + 256 * i] = bv[tid + 256 * i];
}

// ---------------------------------------------------------------------------
// conv: fp32 [T_base | A_mats] -> fp16, INTERLEAVED layout [row][mat][col]
// so a step-wave's 5 per-row streams are one contiguous 40 KB region.
// dst uint4 index = row*RSTRIDE + m*ROWQ + c,  c in [0,512).
// Each thread: 8 consecutive elements of one (m,row). 40960 blocks x 256.
// ---------------------------------------------------------------------------
__global__ __launch_bounds__(256) void conv_kernel(
        const float* __restrict__ Tb, const float* __restrict__ Am,
        uint4* __restrict__ dst) {
    const size_t gid = (size_t)blockIdx.x * 256 + threadIdx.x;  // [0, 5*NN/8)
    const size_t perMat = NN / 8;
    const int    m   = (int)(gid / perMat);
    const size_t rem = gid - (size_t)m * perMat;     // uint4 index inside matrix m
    const int    rw  = (int)(rem >> 9);              // row
    const int    c   = (int)(rem & 511);             // uint4-col

    const float* src = (m == 0) ? Tb : (Am + (size_t)(m - 1) * NN);
    const float4* s4 = (const float4*)src;
    const float4 f0 = s4[rem * 2];
    const float4 f1 = s4[rem * 2 + 1];
    union { uint4 v; __half h[8]; } pk;
    pk.h[0] = __float2half(f0.x); pk.h[1] = __float2half(f0.y);
    pk.h[2] = __float2half(f0.z); pk.h[3] = __float2half(f0.w);
    pk.h[4] = __float2half(f1.x); pk.h[5] = __float2half(f1.y);
    pk.h[6] = __float2half(f1.z); pk.h[7] = __float2half(f1.w);
    dst[(size_t)rw * RSTRIDE + (size_t)m * ROWQ + c] = pk.v;
}

// ---------------------------------------------------------------------------
// One recurrence step, fp16 matrices read DIRECTLY (no materialized T_t):
//   y = (T_base + sum_a act[a] A_a) @ x + b ; x_out = y
// 1025 blocks x 256 threads. Blocks 0..1023: one wave per row; 5 fp32
// accumulators combined with act AFTER the K-loop, ONE shuffle reduction.
// Plain cached loads: the 160 MB fp16 working set is Infinity-Cache-resident,
// L3 retention is the whole play (round-4 FETCH_SIZE proved L3 retains
// ~150 MB of matrix data across dispatches). x read straight from global
// (16 KB, L1-resident) -- no LDS staging, no barrier, no atomics.
// Block 1024: out[t-1] = r . x_in (previous step's reward), atomic-free.
// ---------------------------------------------------------------------------
__global__ __launch_bounds__(256, 4) void step5_kernel(
        const nuint4* __restrict__ M,    // interleaved [row][5][ROWQ]
        const float* __restrict__ x_in,
        float*       __restrict__ x_out,
        const float* __restrict__ b,
        const float* __restrict__ r,
        const float* __restrict__ traj,
        float*       __restrict__ out, int t) {
    const int tid  = threadIdx.x;
    const int wave = tid >> 6, lane = tid & 63;
    __shared__ float parts[4];

    if (blockIdx.x == gridDim.x - 1) {
        float s = 0.f;
#pragma unroll
        for (int i = 0; i < 16; i++) {
            const int idx = tid + 256 * i;
            s = fmaf(r[idx], x_in[idx], s);
        }
#pragma unroll
        for (int off = 32; off > 0; off >>= 1) s += __shfl_xor(s, off, 64);
        if (lane == 0) parts[wave] = s;
        __syncthreads();
        if (tid == 0) out[t - 1] = parts[0] + parts[1] + parts[2] + parts[3];
        return;
    }

    const int row = blockIdx.x * 4 + wave;
    const size_t base = (size_t)row * RSTRIDE;
    const float4* xv = (const float4*)x_in;
    const float4 av = ((const float4*)traj)[t];

    float acc[5] = {0.f, 0.f, 0.f, 0.f, 0.f};
#pragma unroll
    for (int c = 0; c < 8; c++) {
        const int ci = c * 64 + lane;
        const float4 xa = xv[ci * 2];
        const float4 xb = xv[ci * 2 + 1];
#pragma unroll
        for (int m = 0; m < 5; m++) {
            union { nuint4 v; __half2 h2[4]; } u;
            u.v = M[base + (size_t)m * ROWQ + ci];
            const float2 p0 = __half22float2(u.h2[0]);
            const float2 p1 = __half22float2(u.h2[1]);
            const float2 p2 = __half22float2(u.h2[2]);
            const float2 p3 = __half22float2(u.h2[3]);
            float a = acc[m];
            a = fmaf(p0.x, xa.x, a); a = fmaf(p0.y, xa.y, a);
            a = fmaf(p1.x, xa.z, a); a = fmaf(p1.y, xa.w, a);
            a = fmaf(p2.x, xb.x, a); a = fmaf(p2.y, xb.y, a);
            a = fmaf(p3.x, xb.z, a); a = fmaf(p3.y, xb.w, a);
            acc[m] = a;
        }
    }
    float s = acc[0] + av.x * acc[1] + av.y * acc[2] + av.z * acc[3] + av.w * acc[4];
#pragma unroll
    for (int off = 32; off > 0; off >>= 1) s += __shfl_xor(s, off, 64);
    if (lane == 0) x_out[row] = s + b[row];
}

// ---------------------------------------------------------------------------
// final: out[L-1] = r . x_final   (one block)
// ---------------------------------------------------------------------------
__global__ void dot_kernel(const float* __restrict__ x, const float* __restrict__ r,
                           float* __restrict__ out_elem) {
    const int tid = threadIdx.x;
    const int wave = tid >> 6, lane = tid & 63;
    __shared__ float parts[4];
    float s = 0.f;
#pragma unroll
    for (int i = 0; i < 16; i++) {
        const int idx = tid + 256 * i;
        s = fmaf(r[idx], x[idx], s);
    }
#pragma unroll
    for (int off = 32; off > 0; off >>= 1) s += __shfl_xor(s, off, 64);
    if (lane == 0) parts[wave] = s;
    __syncthreads();
    if (tid == 0) *out_elem = parts[0] + parts[1] + parts[2] + parts[3];
}

// ---------------------------------------------------------------------------
// Fallback step (only if ws can't hold the fp16 copy): fp32 sources.
// ---------------------------------------------------------------------------
__global__ __launch_bounds__(256) void step_f32_kernel(
        const float* __restrict__ Tb, const float* __restrict__ Am,
        const float* __restrict__ x_in, float* __restrict__ x_out,
        const float* __restrict__ b, const float* __restrict__ r,
        const float* __restrict__ traj, float* __restrict__ out, int t) {
    const int tid  = threadIdx.x;
    const int wave = tid >> 6, lane = tid & 63;
    __shared__ float parts[4];

    if (blockIdx.x == gridDim.x - 1) {
        float s = 0.f;
#pragma unroll
        for (int i = 0; i < 16; i++) {
            const int idx = tid + 256 * i;
            s = fmaf(r[idx], x_in[idx], s);
        }
#pragma unroll
        for (int off = 32; off > 0; off >>= 1) s += __shfl_xor(s, off, 64);
        if (lane == 0) parts[wave] = s;
        __syncthreads();
        if (tid == 0) out[t - 1] = parts[0] + parts[1] + parts[2] + parts[3];
        return;
    }

    const float a0 = traj[t * ANUM + 0], a1 = traj[t * ANUM + 1],
                a2 = traj[t * ANUM + 2], a3 = traj[t * ANUM + 3];
    const int row = blockIdx.x * 4 + wave;
    const float4* mat[5] = {
        (const float4*)Tb, (const float4*)Am, (const float4*)(Am + NN),
        (const float4*)(Am + 2 * NN), (const float4*)(Am + 3 * NN)};
    const size_t rowq = (size_t)row * (NDIM / 4);
    const float4* xv = (const float4*)x_in;

    float acc[5] = {0.f, 0.f, 0.f, 0.f, 0.f};
#pragma unroll
    for (int c = 0; c < 16; c++) {
        const int ci = c * 64 + lane;
        const float4 xa = xv[ci];
        const size_t qi = rowq + ci;
#pragma unroll
        for (int m = 0; m < 5; m++) {
            const float4 v = mat[m][qi];
            float a = acc[m];
            a = fmaf(v.x, xa.x, a); a = fmaf(v.y, xa.y, a);
            a = fmaf(v.z, xa.z, a); a = fmaf(v.w, xa.w, a);
            acc[m] = a;
        }
    }
    float s = acc[0] + a0 * acc[1] + a1 * acc[2] + a2 * acc[3] + a3 * acc[4];
#pragma unroll
    for (int off = 32; off > 0; off >>= 1) s += __shfl_xor(s, off, 64);
    if (lane == 0) x_out[row] = s + b[row];
}

// ---------------------------------------------------------------------------
extern "C" void kernel_launch(void* const* d_in, const int* in_sizes, int n_in,
                              void* d_out, int out_size, void* d_ws, size_t ws_size,
                              hipStream_t stream) {
    // inputs: init_states(N) [unused], trajectories(L*ANUM), T_base(N*N),
    //         A_mats(ANUM*N*N), b(N), r(N)
    const float* traj = (const float*)d_in[1];
    const float* Tb   = (const float*)d_in[2];
    const float* Am   = (const float*)d_in[3];
    const float* b    = (const float*)d_in[4];
    const float* r    = (const float*)d_in[5];
    float* out = (float*)d_out;

    const size_t matBytes = 5 * NN * sizeof(__half);            // 160 MiB
    const size_t xBytes   = 2 * (size_t)NDIM * sizeof(float);
    const bool useHalf = ws_size >= matBytes + xBytes;

    if (useHalf) {
        uint4* mats = (uint4*)d_ws;
        float* x0 = (float*)((char*)d_ws + matBytes);
        float* x1 = x0 + NDIM;

        init_kernel<<<1, 256, 0, stream>>>(b, x0);  // x0 = x_1 = b
        const int convBlocks = (int)((5 * NN / 8) / 256);        // 40960
        conv_kernel<<<convBlocks, 256, 0, stream>>>(Tb, Am, mats);

        for (int t = 1; t < LSTEPS; t++) {
            float* xi = (t & 1) ? x0 : x1;
            float* xo = (t & 1) ? x1 : x0;
            step5_kernel<<<NDIM / 4 + 1, 256, 0, stream>>>(
                (const nuint4*)mats, xi, xo, b, r, traj, out, t);
        }
        // x_50 was written by step t=49 (odd -> x1)
        dot_kernel<<<1, 256, 0, stream>>>(x1, r, out + (LSTEPS - 1));
    } else {
        float* x0 = (float*)d_ws;
        float* x1 = x0 + NDIM;
        init_kernel<<<1, 256, 0, stream>>>(b, x0);
        for (int t = 1; t < LSTEPS; t++) {
            float* xi = (t & 1) ? x0 : x1;
            float* xo = (t & 1) ? x1 : x0;
            step_f32_kernel<<<NDIM / 4 + 1, 256, 0, stream>>>(Tb, Am, xi, xo, b, r,
                                                              traj, out, t);
        }
        dot_kernel<<<1, 256, 0, stream>>>(x1, r, out + (LSTEPS - 1));
    }
}